// Round 7
// baseline (54.400 us; speedup 1.0000x reference)
//
#include <hip/hip_runtime.h>
#include <hip/hip_fp16.h>

#define N_NODES 100000
#define N_EDGES 600000
#define DIM 128
#define HID 64
#define NPAIRS 3125          // 100000 / 32 exact (pair = two 16-row tiles)

typedef __attribute__((ext_vector_type(8))) _Float16 half8;
typedef __attribute__((ext_vector_type(4))) _Float16 half4v;
typedef __attribute__((ext_vector_type(4))) float floatx4;

#define VMCNT(n) asm volatile("s_waitcnt vmcnt(" #n ")" ::: "memory")

// direct global -> LDS; LDS dest is wave-uniform base, HW adds lane*16.
__device__ __forceinline__ void gload_lds16(const void* g, void* l) {
    __builtin_amdgcn_global_load_lds(
        (const __attribute__((address_space(1))) void*)g,
        (__attribute__((address_space(3))) void*)l, 16, 0, 0);
}

// ---------------------------------------------------------------------------
// Kernel 0: W1T[c][k] (f16, [128][128]) = c<64 ? W1[k][c] : W1[128+k][c-64]
// ---------------------------------------------------------------------------
__global__ __launch_bounds__(256) void prep_W(
    const float* __restrict__ W1, __half* __restrict__ W1T)
{
    const int o = (int)(blockIdx.x * blockDim.x + threadIdx.x) * 2;
    if (o >= 128 * 128) return;
    const int c = o >> 7, k = o & 127;
    float w0, w1;
    if (c < HID) { w0 = W1[k * HID + c];               w1 = W1[(k + 1) * HID + c]; }
    else         { w0 = W1[(DIM + k) * HID + c - HID]; w1 = W1[(DIM + k + 1) * HID + c - HID]; }
    W1T[o]     = __float2half(w0);
    W1T[o + 1] = __float2half(w1);
}

// ---------------------------------------------------------------------------
// Kernel 1: P = node_emb @ Wbig (+b1 on hidden 0..63), f16, permuted layout
// (P-pos p=32m+8q+4t+i <- hidden h=(2m+t)*16+4q+i, t=tile parity).
// NEW: column-split waves. Block = 4 waves; per iteration the block stages
// TWO 16-row tiles (slots 0,1; each wave stages a 4KB quarter) and wave w
// computes slot (w>>1), column half (w&1). wf[4][4]=64 VGPR, acc[4]=16 ->
// ~110 VGPR + 32KB LDS -> 4 blocks/CU, 16 waves/CU (2x R6 occupancy).
// ---------------------------------------------------------------------------
__global__ __launch_bounds__(256, 4) void precompute_P(
    const float* __restrict__ node_emb,
    const __half* __restrict__ W1T,
    const float* __restrict__ b1,
    __half* __restrict__ P)
{
    __shared__ char lds[2][2][8192];     // [dbuf][tile slot][16 rows x 512 B]

    const int tid  = threadIdx.x;
    const int w    = tid >> 6;
    const int lane = tid & 63;
    const int lr   = lane & 15;
    const int q    = lane >> 4;
    const int s    = w >> 1;             // tile slot this wave stages+computes
    const int ch   = w & 1;              // column half (0: cols 0-63, 1: 64-127)

    // W fragments for this wave's 64 cols -> 64 VGPRs
    half8 wf[4][4];
#pragma unroll
    for (int nt = 0; nt < 4; nt++)
#pragma unroll
        for (int ks = 0; ks < 4; ks++)
            wf[nt][ks] = *(const half8*)(W1T + (size_t)(ch * 64 + nt * 16 + lr) * 128 + ks * 32 + q * 8);

    float bias_[4][4];
#pragma unroll
    for (int nt = 0; nt < 4; nt++) {
        if (ch == 0) {
            const float4 b4 = *(const float4*)(b1 + nt * 16 + q * 4);
            bias_[nt][0] = b4.x; bias_[nt][1] = b4.y;
            bias_[nt][2] = b4.z; bias_[nt][3] = b4.w;
        } else {
            bias_[nt][0] = bias_[nt][1] = bias_[nt][2] = bias_[nt][3] = 0.f;
        }
    }

    const int b     = (int)blockIdx.x;
    const int base  = b * 3 + (b < 53 ? b : 53);
    const int quota = 3 + (b < 53 ? 1 : 0);

    const char* nb  = (const char*)node_emb;
    const int h8    = w & 1;             // which 8-row half this wave stages
    const int rhalf = lane >> 5;
    const int in16  = (lane & 31) << 4;

    // wave stages rows [h8*8, h8*8+8) of tile (2*PI + s) into buf B
#define STAGE(PI, B)                                                         \
    {                                                                        \
        _Pragma("unroll")                                                    \
        for (int r = 0; r < 4; r++) {                                        \
            const int row_in = h8 * 8 + 2 * r + rhalf;                       \
            const size_t src = (size_t)((2 * (PI) + s) * 16 + row_in) * 512  \
                             + (size_t)(in16 ^ ((row_in & 7) << 4));         \
            gload_lds16(nb + src,                                            \
                        &lds[B][s][0] + h8 * 4096 + r * 1024);               \
        }                                                                    \
    }

    int pi = base;
    STAGE(pi, 0);

    int cur = 0;
    bool first = true;
    for (; pi < base + quota; pi++, cur ^= 1, first = false) {
        const bool has_next = (pi + 1 < base + quota);
        if (has_next) {
            STAGE(pi + 1, cur ^ 1);
            if (first) { VMCNT(4); } else { VMCNT(6); }   // 2 stores + 4 new loads
        } else {
            VMCNT(0);
        }
        __builtin_amdgcn_s_barrier();

        floatx4 acc[4];
#pragma unroll
        for (int nt = 0; nt < 4; nt++) acc[nt] = (floatx4){0.f, 0.f, 0.f, 0.f};

        const char* Ab = &lds[cur][s][0];
        const int sw = (lr & 7) << 4;
#pragma unroll
        for (int ks = 0; ks < 4; ks++) {
            const int cb = ks * 128 + q * 32;
            const float4 x0 = *(const float4*)(Ab + lr * 512 + ((cb)      ^ sw));
            const float4 x1 = *(const float4*)(Ab + lr * 512 + ((cb + 16) ^ sw));
            half8 af;
            af[0] = (_Float16)x0.x; af[1] = (_Float16)x0.y;
            af[2] = (_Float16)x0.z; af[3] = (_Float16)x0.w;
            af[4] = (_Float16)x1.x; af[5] = (_Float16)x1.y;
            af[6] = (_Float16)x1.z; af[7] = (_Float16)x1.w;
#pragma unroll
            for (int nt = 0; nt < 4; nt++)
                acc[nt] = __builtin_amdgcn_mfma_f32_16x16x32_f16(wf[nt][ks], af, acc[nt], 0, 0, 0);
        }

        // all my ds_reads retired before anyone overwrites this buffer
        asm volatile("s_waitcnt lgkmcnt(0)" ::: "memory");
        __builtin_amdgcn_sched_barrier(0);

        // permuted packed epilogue: 2 x 16B stores (m = 2*ch + mm)
        {
            char* prow = (char*)P + (size_t)((2 * pi + s) * 16 + lr) * 256;
#pragma unroll
            for (int mm = 0; mm < 2; mm++) {
                const int m = 2 * ch + mm;
                half8 hh;
#pragma unroll
                for (int ii = 0; ii < 4; ii++) {
                    const float va = acc[2 * mm][ii]     + bias_[2 * mm][ii];
                    const float vb = acc[2 * mm + 1][ii] + bias_[2 * mm + 1][ii];
                    hh[ii]     = (_Float16)va;
                    hh[ii + 4] = (_Float16)vb;
                }
                *(half8*)(prow + m * 64 + q * 16) = hh;
            }
        }
        __builtin_amdgcn_s_barrier();   // all waves done reading buf[cur]
    }
#undef STAGE
}

// ---------------------------------------------------------------------------
__device__ inline bool detect_int64(const int* e32) {
    int orv = 0;
#pragma unroll
    for (int k = 0; k < 8; k++) orv |= e32[2 * k + 1];
    return orv == 0;
}

// ---------------------------------------------------------------------------
// Kernel 2 (reverted to R2 half-wave): lanes 0-31 edge e, lanes 32-63 edge
// e+1; lane j2 holds P-positions {2j2, 2j2+1} -> hidden {hb, hb+1} via the
// storage permutation; 5-deep xor reduce within each 32-lane half.
// ---------------------------------------------------------------------------
__global__ __launch_bounds__(256) void edge_mlp(
    const __half* __restrict__ P,
    const void* __restrict__ eidx_raw,
    const float* __restrict__ W2,
    const float* __restrict__ b2,
    float* __restrict__ out)
{
    const int* e32 = (const int*)eidx_raw;
    const long long* e64 = (const long long*)eidx_raw;
    const bool is64 = detect_int64(e32);

    const int tid  = threadIdx.x;
    const int lane = tid & 63;
    const int sub  = lane >> 5;
    const int j2   = lane & 31;
    // inverse permutation for P-pos p=2*j2: h = (2m+t)*16 + 4q + i
    const int hb = ((j2 >> 4) * 2 + ((j2 >> 1) & 1)) * 16
                 + (((j2 >> 2) & 3) << 2) + ((j2 & 1) << 1);
    const float w2x = W2[hb];
    const float w2y = W2[hb + 1];
    const float b2v = b2[0];
    const __half2* P2 = (const __half2*)P;   // rows of 64 half2

    const int gwid   = (int)((blockIdx.x * blockDim.x + tid) >> 6);
    const int nwaves = (int)((gridDim.x * blockDim.x) >> 6);

    for (int base = gwid * 8; base < N_EDGES; base += nwaves * 8) {
        int s[4], d[4];
#pragma unroll
        for (int u = 0; u < 4; u++) {
            const int e = base + 2 * u + sub;
            if (is64) { s[u] = (int)e64[e]; d[u] = (int)e64[N_EDGES + e]; }
            else      { s[u] = e32[e];      d[u] = e32[N_EDGES + e]; }
        }
        __half2 av[4], bv[4];
#pragma unroll
        for (int u = 0; u < 4; u++) {
            av[u] = P2[(size_t)s[u] * 64 + j2];
            bv[u] = P2[(size_t)d[u] * 64 + 32 + j2];
        }
#pragma unroll
        for (int u = 0; u < 4; u++) {
            const float2 a = __half22float2(av[u]);
            const float2 b = __half22float2(bv[u]);
            float t = fmaxf(a.x + b.x, 0.f) * w2x
                    + fmaxf(a.y + b.y, 0.f) * w2y;
#pragma unroll
            for (int off = 16; off >= 1; off >>= 1)
                t += __shfl_xor(t, off, 64);
            const float o1 = __shfl(t, 32, 64);
            if (lane == 0)
                *(float2*)(out + base + 2 * u) = make_float2(t + b2v, o1 + b2v);
        }
    }
}

// ---------------------------------------------------------------------------
// Fallback (ws too small): direct per-edge compute, slow but correct.
// ---------------------------------------------------------------------------
__global__ __launch_bounds__(256) void edge_mlp_direct(
    const float* __restrict__ node_emb,
    const void* __restrict__ eidx_raw,
    const float* __restrict__ W1,
    const float* __restrict__ b1,
    const float* __restrict__ W2,
    const float* __restrict__ b2,
    float* __restrict__ out)
{
    const int* e32 = (const int*)eidx_raw;
    const long long* e64 = (const long long*)eidx_raw;
    const bool is64 = detect_int64(e32);

    const int lane = threadIdx.x & 63;
    const float w2  = W2[lane];
    const float b2v = b2[0];
    const int gwid   = (int)((blockIdx.x * blockDim.x + threadIdx.x) >> 6);
    const int nwaves = (int)((gridDim.x * blockDim.x) >> 6);

    for (int e = gwid; e < N_EDGES; e += nwaves) {
        int s, d;
        if (is64) { s = (int)e64[e]; d = (int)e64[N_EDGES + e]; }
        else      { s = e32[e];      d = e32[N_EDGES + e]; }
        const float* es = node_emb + (size_t)s * DIM;
        const float* ed = node_emb + (size_t)d * DIM;
        float acc = b1[lane];
        for (int k = 0; k < DIM; k++) {
            acc += es[k] * W1[k * HID + lane];
            acc += ed[k] * W1[(DIM + k) * HID + lane];
        }
        float t = fmaxf(acc, 0.f) * w2;
#pragma unroll
        for (int off = 32; off >= 1; off >>= 1)
            t += __shfl_xor(t, off, 64);
        if (lane == 0) out[e] = t + b2v;
    }
}

// ---------------------------------------------------------------------------
extern "C" void kernel_launch(void* const* d_in, const int* in_sizes, int n_in,
                              void* d_out, int out_size, void* d_ws, size_t ws_size,
                              hipStream_t stream) {
    const float* node_emb = (const float*)d_in[0];
    const void*  eidx     = d_in[1];
    const float* W1       = (const float*)d_in[2];
    const float* b1       = (const float*)d_in[3];
    const float* W2       = (const float*)d_in[4];
    const float* b2       = (const float*)d_in[5];
    float* out = (float*)d_out;

    const size_t wt_off = 32u * 1024 * 1024;
    const size_t need   = wt_off + 128 * 128 * sizeof(__half);

    if (ws_size >= need) {
        __half* P   = (__half*)d_ws;
        __half* W1T = (__half*)((char*)d_ws + wt_off);
        prep_W<<<32, 256, 0, stream>>>(W1, W1T);
        precompute_P<<<1024, 256, 0, stream>>>(node_emb, W1T, b1, P);
        edge_mlp<<<2048, 256, 0, stream>>>(P, eidx, W2, b2, out);
    } else {
        edge_mlp_direct<<<4096, 256, 0, stream>>>(node_emb, eidx, W1, b1, W2, b2, out);
    }
}